// Round 5
// baseline (194.868 us; speedup 1.0000x reference)
//
#include <hip/hip_runtime.h>
#include <hip/hip_bf16.h>

typedef _Float16 f16x8 __attribute__((ext_vector_type(8)));
typedef float f32x4 __attribute__((ext_vector_type(4)));

#define BM 64       // rows per block
#define NF 16       // features per K-chunk
#define BKH 192     // K-halves per chunk (16 features x 12 slots)
#define LDA 200     // padded LDS row stride (halves): 400B
#define NCHUNK 16   // 256 features / 16
#define IN_F 256
#define OUT_F 256
#define KDIM 3072   // 256 * 12

// Build W2[o][k] fp16, k = i*12 + m ; m<11 -> coeff[o][i][m], m==11 -> base_w[o][i]
__global__ __launch_bounds__(256) void prep_w(const float* __restrict__ coeff,
                                              const float* __restrict__ base_w,
                                              _Float16* __restrict__ W2) {
  const int o = blockIdx.x;
  for (int k2 = threadIdx.x; k2 < KDIM / 2; k2 += 256) {
    const int k = k2 * 2;
    float v0, v1;
    {
      const int i = k / 12, m = k % 12;
      v0 = (m == 11) ? base_w[o * IN_F + i] : coeff[(o * IN_F + i) * 11 + m];
    }
    {
      const int k1 = k + 1;
      const int i = k1 / 12, m = k1 % 12;
      v1 = (m == 11) ? base_w[o * IN_F + i] : coeff[(o * IN_F + i) * 11 + m];
    }
    union { _Float16 h[2]; unsigned int u; } p;
    p.h[0] = (_Float16)v0;
    p.h[1] = (_Float16)v1;
    *(unsigned int*)&W2[(size_t)o * KDIM + k] = p.u;
  }
}

__global__ __launch_bounds__(512, 4) void kan_fused(const float* __restrict__ x,
                                                    const float* __restrict__ gamma,
                                                    const float* __restrict__ beta,
                                                    const _Float16* __restrict__ W2,
                                                    float* __restrict__ out) {
  __shared__ _Float16 A0[BM * LDA];   // double-buffered A tile
  __shared__ _Float16 A1[BM * LDA];
  __shared__ float mu_s[BM], rs_s[BM];
  __shared__ float g_s[IN_F], b_s[IN_F];

  const int tid  = threadIdx.x;
  const int lane = tid & 63;
  const int wid  = tid >> 6;          // 0..7
  const int row0 = blockIdx.x * BM;

  // gamma/beta to LDS
  if (tid < IN_F) g_s[tid] = gamma[tid];
  else            b_s[tid - IN_F] = beta[tid - IN_F];

  // ---- LayerNorm stats: one wave per row ----
  for (int rr = wid; rr < BM; rr += 8) {
    const float4 v = *(const float4*)(x + (size_t)(row0 + rr) * IN_F + lane * 4);
    float s  = v.x + v.y + v.z + v.w;
    float sq = v.x * v.x + v.y * v.y + v.z * v.z + v.w * v.w;
    #pragma unroll
    for (int off = 32; off >= 1; off >>= 1) {
      s  += __shfl_xor(s, off);
      sq += __shfl_xor(sq, off);
    }
    if (lane == 0) {
      const float mu  = s * (1.0f / 256.0f);
      const float var = sq * (1.0f / 256.0f) - mu * mu;
      mu_s[rr] = mu;
      rs_s[rr] = 1.0f / sqrtf(var + 1e-5f);
    }
  }

  // wave tile: 2(M) x 4(N) waves, each 32 rows x 64 cols
  const int wr   = wid >> 2;          // 0..1
  const int wc   = wid & 3;           // 0..3
  const int lrow = lane & 15;
  const int lk8  = (lane >> 4) * 8;

  f32x4 acc[2][4] = {};

  // production: 64 rows x 8 feature-pairs = 512 cells, 1 per thread
  const int prow = tid >> 3;          // 0..63
  const int pfq  = tid & 7;           // feature-pair within chunk

  const _Float16* wbase = W2 + (size_t)(wc * 64 + lrow) * KDIM + lk8;

  auto produce = [&](int c, _Float16* buf) {
    const int i = c * NF + pfq * 2;
    const float2 xv = *(const float2*)(x + (size_t)(row0 + prow) * IN_F + i);
    const float mu = mu_s[prow], rs = rs_s[prow];
    _Float16 h[24];
    #pragma unroll
    for (int q = 0; q < 2; ++q) {
      const float xr = (q == 0) ? xv.x : xv.y;
      const float n  = (xr - mu) * rs * g_s[i + q] + b_s[i + q];
      const float v  = (n + 1.75f) * 4.0f;      // knots t_j = -1.75 + 0.25*j
      const float fj = floorf(v);
      const int j = (v >= 0.0f && v < 14.0f) ? (int)fj : 999; // out of grid -> zero basis
      const float u  = v - fj;
      const float u2 = u * u, u3 = u2 * u;
      const float w0 = (1.0f / 6.0f) * (1.0f - 3.0f * u + 3.0f * u2 - u3);
      const float w1 = (1.0f / 6.0f) * (3.0f * u3 - 6.0f * u2 + 4.0f);
      const float w2 = (1.0f / 6.0f) * (-3.0f * u3 + 3.0f * u2 + 3.0f * u + 1.0f);
      const float w3 = (1.0f / 6.0f) * u3;
      #pragma unroll
      for (int m = 0; m < 11; ++m) {            // tap index t = m - (j-3)
        const int t = m - j + 3;
        float w = 0.0f;
        w = (t == 0) ? w0 : w;
        w = (t == 1) ? w1 : w;
        w = (t == 2) ? w2 : w;
        w = (t == 3) ? w3 : w;
        h[q * 12 + m] = (_Float16)w;
      }
      h[q * 12 + 11] = (_Float16)(xr / (1.0f + __expf(-xr)));  // silu(raw x)
    }
    char* db = (char*)&buf[prow * LDA] + pfq * 48;
    *(f16x8*)(db)      = *(const f16x8*)&h[0];
    *(f16x8*)(db + 16) = *(const f16x8*)&h[8];
    *(f16x8*)(db + 32) = *(const f16x8*)&h[16];
  };

  auto domfma = [&](int c, const _Float16* buf) {
    const _Float16* wk = wbase + c * BKH;
    #pragma unroll
    for (int fk = 0; fk < 6; ++fk) {
      f16x8 a[2], b[4];
      #pragma unroll
      for (int fm = 0; fm < 2; ++fm)
        a[fm] = *(const f16x8*)&buf[(wr * 32 + fm * 16 + lrow) * LDA + fk * 32 + lk8];
      #pragma unroll
      for (int fn = 0; fn < 4; ++fn)
        b[fn] = *(const f16x8*)(wk + (size_t)fn * 16 * KDIM + fk * 32);
      #pragma unroll
      for (int fm = 0; fm < 2; ++fm)
        #pragma unroll
        for (int fn = 0; fn < 4; ++fn)
          acc[fm][fn] = __builtin_amdgcn_mfma_f32_16x16x32_f16(a[fm], b[fn], acc[fm][fn], 0, 0, 0);
    }
  };

  __syncthreads();                    // stats + gamma/beta visible
  produce(0, A0);
  __syncthreads();

  for (int c = 0; c < NCHUNK; c += 2) {
    // interval 1: produce(c+1)->A1 overlaps mfma(c)<-A0
    produce(c + 1, A1);
    domfma(c, A0);
    __syncthreads();
    // interval 2: produce(c+2)->A0 overlaps mfma(c+1)<-A1
    if (c + 2 < NCHUNK) produce(c + 2, A0);
    domfma(c + 1, A1);
    __syncthreads();
  }

  // ---- epilogue: D lane layout col = lane&15, row = (lane>>4)*4 + r ----
  const int orow0 = row0 + wr * 32 + (lane >> 4) * 4;
  const int ocol0 = wc * 64 + lrow;
  #pragma unroll
  for (int fm = 0; fm < 2; ++fm)
    #pragma unroll
    for (int fn = 0; fn < 4; ++fn)
      #pragma unroll
      for (int r = 0; r < 4; ++r)
        out[(size_t)(orow0 + fm * 16 + r) * OUT_F + ocol0 + fn * 16] = acc[fm][fn][r];
}

extern "C" void kernel_launch(void* const* d_in, const int* in_sizes, int n_in,
                              void* d_out, int out_size, void* d_ws, size_t ws_size,
                              hipStream_t stream) {
  const float* x      = (const float*)d_in[0];
  const float* gamma  = (const float*)d_in[1];
  const float* beta   = (const float*)d_in[2];
  const float* coeff  = (const float*)d_in[3];
  const float* base_w = (const float*)d_in[4];
  float* out = (float*)d_out;
  _Float16* W2 = (_Float16*)d_ws;   // 3072*256*2 = 1.5 MB of workspace

  prep_w<<<dim3(OUT_F), dim3(256), 0, stream>>>(coeff, base_w, W2);
  kan_fused<<<dim3(32768 / BM), dim3(512), 0, stream>>>(x, gamma, beta, W2, out);
}

// Round 6
// 156.609 us; speedup vs baseline: 1.2443x; 1.2443x over previous
//
#include <hip/hip_runtime.h>
#include <hip/hip_bf16.h>

typedef _Float16 f16x8 __attribute__((ext_vector_type(8)));
typedef float f32x4 __attribute__((ext_vector_type(4)));

#define BM 64       // rows per block
#define BKH 96      // K-halves per chunk (8 features x 12 slots)
#define LDA 104     // padded LDS row stride (halves): 208B
#define NCH 16      // chunks per K-half (16 x 8 = 128 features per half)
#define IN_F 256
#define OUT_F 256
#define KDIM 3072   // 256 * 12
#define KHALF 1536  // K-halves per ks-slice

// Build W2[o][k] fp16, k = i*12 + m ; m<11 -> coeff[o][i][m], m==11 -> base_w[o][i]
__global__ __launch_bounds__(256) void prep_w(const float* __restrict__ coeff,
                                              const float* __restrict__ base_w,
                                              _Float16* __restrict__ W2) {
  const int o = blockIdx.x;
  for (int k2 = threadIdx.x; k2 < KDIM / 2; k2 += 256) {
    const int k = k2 * 2;
    float v0, v1;
    {
      const int i = k / 12, m = k % 12;
      v0 = (m == 11) ? base_w[o * IN_F + i] : coeff[(o * IN_F + i) * 11 + m];
    }
    {
      const int k1 = k + 1;
      const int i = k1 / 12, m = k1 % 12;
      v1 = (m == 11) ? base_w[o * IN_F + i] : coeff[(o * IN_F + i) * 11 + m];
    }
    union { _Float16 h[2]; unsigned int u; } p;
    p.h[0] = (_Float16)v0;
    p.h[1] = (_Float16)v1;
    *(unsigned int*)&W2[(size_t)o * KDIM + k] = p.u;
  }
}

__global__ __launch_bounds__(512, 4) void kan_fused(const float* __restrict__ x,
                                                    const float* __restrict__ gamma,
                                                    const float* __restrict__ beta,
                                                    const _Float16* __restrict__ W2,
                                                    float* __restrict__ out) {
  __shared__ _Float16 A0[BM * LDA], A1[BM * LDA];   // half-0 double buffer
  __shared__ _Float16 A2[BM * LDA], A3[BM * LDA];   // half-1 double buffer
  __shared__ float red[4][16][64];                  // ks-reduction staging (16 KB)
  __shared__ float mu_s[BM], rs_s[BM];
  __shared__ float g_s[IN_F], b_s[IN_F];

  const int tid  = threadIdx.x;
  const int lane = tid & 63;
  const int wid  = tid >> 6;          // 0..7
  const int row0 = blockIdx.x * BM;

  if (tid < IN_F) g_s[tid] = gamma[tid];
  else            b_s[tid - IN_F] = beta[tid - IN_F];

  // ---- LayerNorm stats: one wave per row ----
  for (int rr = wid; rr < BM; rr += 8) {
    const float4 v = *(const float4*)(x + (size_t)(row0 + rr) * IN_F + lane * 4);
    float s  = v.x + v.y + v.z + v.w;
    float sq = v.x * v.x + v.y * v.y + v.z * v.z + v.w * v.w;
    #pragma unroll
    for (int off = 32; off >= 1; off >>= 1) {
      s  += __shfl_xor(s, off);
      sq += __shfl_xor(sq, off);
    }
    if (lane == 0) {
      const float mu  = s * (1.0f / 256.0f);
      const float var = sq * (1.0f / 256.0f) - mu * mu;
      mu_s[rr] = mu;
      rs_s[rr] = 1.0f / sqrtf(var + 1e-5f);
    }
  }
  __syncthreads();                    // stats + gamma/beta visible

  // waves: ks = K-slice (0..1), wc = output-col group (0..3); each wave 64x64 out
  const int ks   = wid >> 2;
  const int wc   = wid & 3;
  const int lrow = lane & 15;
  const int lk8  = (lane >> 4) * 8;

  f32x4 acc[4][4] = {};

  // production (per 256-thread half): 64 rows x 4 feature-pairs
  const int ptid = tid & 255;
  const int prow = ptid >> 2;
  const int pfq  = ptid & 3;
  const int ibase = ks * 128 + pfq * 2;         // this half's feature base
  const float mu = mu_s[prow], rs = rs_s[prow]; // hoisted once

  _Float16* Ae = ks ? A2 : A0;
  _Float16* Ao = ks ? A3 : A1;

  const _Float16* wbase = W2 + (size_t)(wc * 64 + lrow) * KDIM + ks * KHALF + lk8;
  const float* xrow = x + (size_t)(row0 + prow) * IN_F + ibase;

  auto produce = [&](_Float16* buf, float2 xv, float2 gv, float2 bv) {
    _Float16 h[24];
    #pragma unroll
    for (int q = 0; q < 2; ++q) {
      const float xr = (q == 0) ? xv.x : xv.y;
      const float gq = (q == 0) ? gv.x : gv.y;
      const float bq = (q == 0) ? bv.x : bv.y;
      const float n  = (xr - mu) * rs * gq + bq;
      const float v  = (n + 1.75f) * 4.0f;      // knots t_j = -1.75 + 0.25*j
      const float fj = floorf(v);
      const int j = (v >= 0.0f && v < 14.0f) ? (int)fj : 999; // out of grid -> zero basis
      const float u  = v - fj;
      const float u2 = u * u, u3 = u2 * u;
      const float w0 = (1.0f / 6.0f) * (1.0f - 3.0f * u + 3.0f * u2 - u3);
      const float w1 = (1.0f / 6.0f) * (3.0f * u3 - 6.0f * u2 + 4.0f);
      const float w2 = (1.0f / 6.0f) * (-3.0f * u3 + 3.0f * u2 + 3.0f * u + 1.0f);
      const float w3 = (1.0f / 6.0f) * u3;
      #pragma unroll
      for (int m = 0; m < 11; ++m) {            // tap index t = m - (j-3)
        const int t = m - j + 3;
        float w = 0.0f;
        w = (t == 0) ? w0 : w;
        w = (t == 1) ? w1 : w;
        w = (t == 2) ? w2 : w;
        w = (t == 3) ? w3 : w;
        h[q * 12 + m] = (_Float16)w;
      }
      h[q * 12 + 11] = (_Float16)(xr / (1.0f + __expf(-xr)));  // silu(raw x)
    }
    char* db = (char*)&buf[prow * LDA] + pfq * 48;
    *(f16x8*)(db)      = *(const f16x8*)&h[0];
    *(f16x8*)(db + 16) = *(const f16x8*)&h[8];
    *(f16x8*)(db + 32) = *(const f16x8*)&h[16];
  };

  auto domfma = [&](int c, const _Float16* buf) {
    const _Float16* wk = wbase + c * BKH;
    #pragma unroll
    for (int fk = 0; fk < 3; ++fk) {
      f16x8 a[4], b[4];
      #pragma unroll
      for (int fm = 0; fm < 4; ++fm)
        a[fm] = *(const f16x8*)&buf[(fm * 16 + lrow) * LDA + fk * 32 + lk8];
      #pragma unroll
      for (int fn = 0; fn < 4; ++fn)
        b[fn] = *(const f16x8*)(wk + (size_t)fn * 16 * KDIM + fk * 32);
      #pragma unroll
      for (int fm = 0; fm < 4; ++fm)
        #pragma unroll
        for (int fn = 0; fn < 4; ++fn)
          acc[fm][fn] = __builtin_amdgcn_mfma_f32_16x16x32_f16(a[fm], b[fn], acc[fm][fn], 0, 0, 0);
    }
  };

  // prefetch chunks 0 and 1 into registers
  float2 xv0 = *(const float2*)(xrow);
  float2 gv0 = *(const float2*)&g_s[ibase];
  float2 bv0 = *(const float2*)&b_s[ibase];
  float2 xv1 = *(const float2*)(xrow + 8);
  float2 gv1 = *(const float2*)&g_s[ibase + 8];
  float2 bv1 = *(const float2*)&b_s[ibase + 8];

  produce(Ae, xv0, gv0, bv0);
  __syncthreads();

  for (int c = 0; c < NCH; c += 2) {
    // interval A: prefetch c+2; produce(c+1)->Ao; mfma(c)<-Ae
    if (c + 2 < NCH) {
      xv0 = *(const float2*)(xrow + (c + 2) * 8);
      gv0 = *(const float2*)&g_s[ibase + (c + 2) * 8];
      bv0 = *(const float2*)&b_s[ibase + (c + 2) * 8];
    }
    produce(Ao, xv1, gv1, bv1);
    domfma(c, Ae);
    __syncthreads();
    // interval B: prefetch c+3; produce(c+2)->Ae; mfma(c+1)<-Ao
    if (c + 3 < NCH) {
      xv1 = *(const float2*)(xrow + (c + 3) * 8);
      gv1 = *(const float2*)&g_s[ibase + (c + 3) * 8];
      bv1 = *(const float2*)&b_s[ibase + (c + 3) * 8];
    }
    if (c + 2 < NCH) produce(Ae, xv0, gv0, bv0);
    domfma(c + 1, Ao);
    __syncthreads();
  }

  // ---- ks-reduction + store: 4 passes over fm through 16KB LDS ----
  #pragma unroll
  for (int fm = 0; fm < 4; ++fm) {
    if (ks == 1) {
      #pragma unroll
      for (int fn = 0; fn < 4; ++fn)
        #pragma unroll
        for (int r = 0; r < 4; ++r)
          red[wc][fn * 4 + r][lane] = acc[fm][fn][r];
    }
    __syncthreads();
    if (ks == 0) {
      #pragma unroll
      for (int fn = 0; fn < 4; ++fn)
        #pragma unroll
        for (int r = 0; r < 4; ++r) {
          const float v = acc[fm][fn][r] + red[wc][fn * 4 + r][lane];
          out[(size_t)(row0 + fm * 16 + (lane >> 4) * 4 + r) * OUT_F + wc * 64 + fn * 16 + lrow] = v;
        }
    }
    __syncthreads();
  }
}

extern "C" void kernel_launch(void* const* d_in, const int* in_sizes, int n_in,
                              void* d_out, int out_size, void* d_ws, size_t ws_size,
                              hipStream_t stream) {
  const float* x      = (const float*)d_in[0];
  const float* gamma  = (const float*)d_in[1];
  const float* beta   = (const float*)d_in[2];
  const float* coeff  = (const float*)d_in[3];
  const float* base_w = (const float*)d_in[4];
  float* out = (float*)d_out;
  _Float16* W2 = (_Float16*)d_ws;   // 3072*256*2 = 1.5 MB of workspace

  prep_w<<<dim3(OUT_F), dim3(256), 0, stream>>>(coeff, base_w, W2);
  kan_fused<<<dim3(32768 / BM), dim3(512), 0, stream>>>(x, gamma, beta, W2, out);
}

// Round 7
// 128.690 us; speedup vs baseline: 1.5142x; 1.2169x over previous
//
#include <hip/hip_runtime.h>
#include <hip/hip_bf16.h>

typedef _Float16 f16x8 __attribute__((ext_vector_type(8)));
typedef float f32x4 __attribute__((ext_vector_type(4)));

#define BM 64       // rows per block
#define BKH 96      // K-halves per chunk (8 features x 12 slots)
#define LDA 104     // padded LDS row stride (halves): 208B
#define NCHUNK 32   // 3072 / 96
#define IN_F 256
#define OUT_F 256
#define KDIM 3072   // 256 * 12

// Build W2[o][k] fp16, k = i*12 + m ; m<11 -> coeff[o][i][m], m==11 -> base_w[o][i]
__global__ __launch_bounds__(256) void prep_w(const float* __restrict__ coeff,
                                              const float* __restrict__ base_w,
                                              _Float16* __restrict__ W2) {
  const int o = blockIdx.x;
  for (int k2 = threadIdx.x; k2 < KDIM / 2; k2 += 256) {
    const int k = k2 * 2;
    float v0, v1;
    {
      const int i = k / 12, m = k % 12;
      v0 = (m == 11) ? base_w[o * IN_F + i] : coeff[(o * IN_F + i) * 11 + m];
    }
    {
      const int k1 = k + 1;
      const int i = k1 / 12, m = k1 % 12;
      v1 = (m == 11) ? base_w[o * IN_F + i] : coeff[(o * IN_F + i) * 11 + m];
    }
    union { _Float16 h[2]; unsigned int u; } p;
    p.h[0] = (_Float16)v0;
    p.h[1] = (_Float16)v1;
    *(unsigned int*)&W2[(size_t)o * KDIM + k] = p.u;
  }
}

__global__ __launch_bounds__(256, 2) void kan_fused(const float* __restrict__ x,
                                                    const float* __restrict__ gamma,
                                                    const float* __restrict__ beta,
                                                    const _Float16* __restrict__ W2,
                                                    float* __restrict__ out) {
  __shared__ _Float16 A0[BM * LDA];   // double-buffered A tile
  __shared__ _Float16 A1[BM * LDA];
  __shared__ float mu_s[BM], rs_s[BM];
  __shared__ float g_s[IN_F], b_s[IN_F];

  const int tid  = threadIdx.x;
  const int lane = tid & 63;
  const int wid  = tid >> 6;          // 0..3
  const int row0 = blockIdx.x * BM;

  // gamma/beta to LDS (256 threads cover 256 features)
  g_s[tid] = gamma[tid];
  b_s[tid] = beta[tid];

  // ---- LayerNorm stats: one wave per row ----
  for (int rr = wid; rr < BM; rr += 4) {
    const float4 v = *(const float4*)(x + (size_t)(row0 + rr) * IN_F + lane * 4);
    float s  = v.x + v.y + v.z + v.w;
    float sq = v.x * v.x + v.y * v.y + v.z * v.z + v.w * v.w;
    #pragma unroll
    for (int off = 32; off >= 1; off >>= 1) {
      s  += __shfl_xor(s, off);
      sq += __shfl_xor(sq, off);
    }
    if (lane == 0) {
      const float mu  = s * (1.0f / 256.0f);
      const float var = sq * (1.0f / 256.0f) - mu * mu;
      mu_s[rr] = mu;
      rs_s[rr] = 1.0f / sqrtf(var + 1e-5f);
    }
  }
  __syncthreads();                    // stats + gamma/beta visible

  // wave tile: 4 waves across N, each 64 rows x 64 cols
  const int wc   = wid;               // 0..3
  const int lrow = lane & 15;
  const int lk8  = (lane >> 4) * 8;

  f32x4 acc[4][4] = {};

  // production mapping: 64 rows x 4 feature-pairs = 256 cells x 2 per thread
  const int prow = tid >> 2;          // 0..63
  const int pfq  = tid & 3;           // feature-pair within chunk
  const float mu = mu_s[prow], rs = rs_s[prow];   // hoisted once

  const _Float16* wbase = W2 + (size_t)(wc * 64 + lrow) * KDIM + lk8;
  const float* xrow = x + (size_t)(row0 + prow) * IN_F + pfq * 2;

  auto produce = [&](int c, _Float16* buf, float2 xv) {
    const int i = c * 8 + pfq * 2;
    _Float16 h[24];
    #pragma unroll
    for (int q = 0; q < 2; ++q) {
      const float xr = (q == 0) ? xv.x : xv.y;
      const float n  = (xr - mu) * rs * g_s[i + q] + b_s[i + q];
      const float v  = (n + 1.75f) * 4.0f;      // knots t_j = -1.75 + 0.25*j
      const float fj = floorf(v);
      const int j = (v >= 0.0f && v < 14.0f) ? (int)fj : 999; // out of grid -> zero basis
      const float u  = v - fj;
      const float u2 = u * u, u3 = u2 * u;
      const float w0 = (1.0f / 6.0f) * (1.0f - 3.0f * u + 3.0f * u2 - u3);
      const float w1 = (1.0f / 6.0f) * (3.0f * u3 - 6.0f * u2 + 4.0f);
      const float w2 = (1.0f / 6.0f) * (-3.0f * u3 + 3.0f * u2 + 3.0f * u + 1.0f);
      const float w3 = (1.0f / 6.0f) * u3;
      #pragma unroll
      for (int m = 0; m < 11; ++m) {            // tap index t = m - (j-3)
        const int t = m - j + 3;
        float w = 0.0f;
        w = (t == 0) ? w0 : w;
        w = (t == 1) ? w1 : w;
        w = (t == 2) ? w2 : w;
        w = (t == 3) ? w3 : w;
        h[q * 12 + m] = (_Float16)w;
      }
      h[q * 12 + 11] = (_Float16)(xr / (1.0f + __expf(-xr)));  // silu(raw x)
    }
    char* db = (char*)&buf[prow * LDA] + pfq * 48;
    *(f16x8*)(db)      = *(const f16x8*)&h[0];
    *(f16x8*)(db + 16) = *(const f16x8*)&h[8];
    *(f16x8*)(db + 32) = *(const f16x8*)&h[16];
  };

  auto loadB = [&](int c, f16x8* bf) {
    const _Float16* wk = wbase + c * BKH;
    #pragma unroll
    for (int fk = 0; fk < 3; ++fk)
      #pragma unroll
      for (int fn = 0; fn < 4; ++fn)
        bf[fk * 4 + fn] = *(const f16x8*)(wk + (size_t)fn * 16 * KDIM + fk * 32);
  };

  auto domfma = [&](const _Float16* buf, const f16x8* bf) {
    #pragma unroll
    for (int fk = 0; fk < 3; ++fk) {
      f16x8 a[4];
      #pragma unroll
      for (int fm = 0; fm < 4; ++fm)
        a[fm] = *(const f16x8*)&buf[(fm * 16 + lrow) * LDA + fk * 32 + lk8];
      #pragma unroll
      for (int fm = 0; fm < 4; ++fm)
        #pragma unroll
        for (int fn = 0; fn < 4; ++fn)
          acc[fm][fn] = __builtin_amdgcn_mfma_f32_16x16x32_f16(a[fm], bf[fk * 4 + fn], acc[fm][fn], 0, 0, 0);
    }
  };

  // prologue: B for chunk 0 in flight; x for chunks 0,1 in flight
  f16x8 bA[12], bB[12];
  loadB(0, bA);
  float2 xv0 = *(const float2*)(xrow);
  float2 xv1 = *(const float2*)(xrow + 8);

  produce(0, A0, xv0);
  __syncthreads();

  for (int c = 0; c < NCHUNK; c += 2) {
    // interval 1: issue B(c+1), x(c+2); produce(c+1)->A1; mfma(c)<-A0,bA
    loadB(c + 1, bB);
    if (c + 2 < NCHUNK) xv0 = *(const float2*)(xrow + (c + 2) * 8);
    produce(c + 1, A1, xv1);
    domfma(A0, bA);
    __syncthreads();
    // interval 2: issue B(c+2), x(c+3); produce(c+2)->A0; mfma(c+1)<-A1,bB
    if (c + 2 < NCHUNK) loadB(c + 2, bA);
    if (c + 3 < NCHUNK) xv1 = *(const float2*)(xrow + (c + 3) * 8);
    if (c + 2 < NCHUNK) produce(c + 2, A0, xv0);
    domfma(A1, bB);
    __syncthreads();
  }

  // ---- epilogue: D lane layout col = lane&15, row = (lane>>4)*4 + r ----
  const int orow0 = row0 + (lane >> 4) * 4;
  const int ocol0 = wc * 64 + lrow;
  #pragma unroll
  for (int fm = 0; fm < 4; ++fm)
    #pragma unroll
    for (int fn = 0; fn < 4; ++fn)
      #pragma unroll
      for (int r = 0; r < 4; ++r)
        out[(size_t)(orow0 + fm * 16 + r) * OUT_F + ocol0 + fn * 16] = acc[fm][fn][r];
}

extern "C" void kernel_launch(void* const* d_in, const int* in_sizes, int n_in,
                              void* d_out, int out_size, void* d_ws, size_t ws_size,
                              hipStream_t stream) {
  const float* x      = (const float*)d_in[0];
  const float* gamma  = (const float*)d_in[1];
  const float* beta   = (const float*)d_in[2];
  const float* coeff  = (const float*)d_in[3];
  const float* base_w = (const float*)d_in[4];
  float* out = (float*)d_out;
  _Float16* W2 = (_Float16*)d_ws;   // 3072*256*2 = 1.5 MB of workspace

  prep_w<<<dim3(OUT_F), dim3(256), 0, stream>>>(coeff, base_w, W2);
  kan_fused<<<dim3(32768 / BM), dim3(256), 0, stream>>>(x, gamma, beta, W2, out);
}

// Round 8
// 128.165 us; speedup vs baseline: 1.5204x; 1.0041x over previous
//
#include <hip/hip_runtime.h>
#include <hip/hip_bf16.h>

typedef _Float16 f16x8 __attribute__((ext_vector_type(8)));
typedef float f32x4 __attribute__((ext_vector_type(4)));

#define BM 64       // rows per block
#define BKH 96      // K-halves per chunk (8 features x 12 slots)
#define LDA 104     // padded LDS row stride (halves): 208B; halves 96..103 = pad/dump
#define NCHUNK 32   // 3072 / 96
#define IN_F 256
#define OUT_F 256
#define KDIM 3072   // 256 * 12

static __device__ inline unsigned pack2(float a, float b) {
  union { _Float16 h[2]; unsigned u; } t;
  t.h[0] = (_Float16)a;
  t.h[1] = (_Float16)b;
  return t.u;
}

// Build W2[o][k] fp16, k = i*12 + m ; m<11 -> coeff[o][i][m], m==11 -> base_w[o][i]
__global__ __launch_bounds__(256) void prep_w(const float* __restrict__ coeff,
                                              const float* __restrict__ base_w,
                                              _Float16* __restrict__ W2) {
  const int o = blockIdx.x;
  for (int k2 = threadIdx.x; k2 < KDIM / 2; k2 += 256) {
    const int k = k2 * 2;
    float v0, v1;
    {
      const int i = k / 12, m = k % 12;
      v0 = (m == 11) ? base_w[o * IN_F + i] : coeff[(o * IN_F + i) * 11 + m];
    }
    {
      const int k1 = k + 1;
      const int i = k1 / 12, m = k1 % 12;
      v1 = (m == 11) ? base_w[o * IN_F + i] : coeff[(o * IN_F + i) * 11 + m];
    }
    union { _Float16 h[2]; unsigned int u; } p;
    p.h[0] = (_Float16)v0;
    p.h[1] = (_Float16)v1;
    *(unsigned int*)&W2[(size_t)o * KDIM + k] = p.u;
  }
}

__global__ __launch_bounds__(256, 2) void kan_fused(const float* __restrict__ x,
                                                    const float* __restrict__ gamma,
                                                    const float* __restrict__ beta,
                                                    const _Float16* __restrict__ W2,
                                                    float* __restrict__ out) {
  __shared__ _Float16 A0[BM * LDA];   // double-buffered A tile
  __shared__ _Float16 A1[BM * LDA];
  __shared__ float mu_s[BM], rs_s[BM];
  __shared__ float g_s[IN_F], b_s[IN_F];

  const int tid  = threadIdx.x;
  const int lane = tid & 63;
  const int wid  = tid >> 6;          // 0..3
  const int row0 = blockIdx.x * BM;

  g_s[tid] = gamma[tid];
  b_s[tid] = beta[tid];

  // ---- LayerNorm stats: one wave per row ----
  for (int rr = wid; rr < BM; rr += 4) {
    const float4 v = *(const float4*)(x + (size_t)(row0 + rr) * IN_F + lane * 4);
    float s  = v.x + v.y + v.z + v.w;
    float sq = v.x * v.x + v.y * v.y + v.z * v.z + v.w * v.w;
    #pragma unroll
    for (int off = 32; off >= 1; off >>= 1) {
      s  += __shfl_xor(s, off);
      sq += __shfl_xor(sq, off);
    }
    if (lane == 0) {
      const float mu  = s * (1.0f / 256.0f);
      const float var = sq * (1.0f / 256.0f) - mu * mu;
      mu_s[rr] = mu;
      rs_s[rr] = 1.0f / sqrtf(var + 1e-5f);
    }
  }
  __syncthreads();                    // stats + gamma/beta visible

  // wave tile: 4 waves across N, each 64 rows x 64 cols
  const int wc   = wid;
  const int lrow = lane & 15;
  const int lk8  = (lane >> 4) * 8;

  f32x4 acc[4][4] = {};

  // production mapping: 64 rows x 4 feature-pairs
  const int prow = tid >> 2;          // 0..63
  const int pfq  = tid & 3;           // feature-pair within chunk
  const float mu = mu_s[prow], rs = rs_s[prow];

  const _Float16* wbase = W2 + (size_t)(wc * 64 + lrow) * KDIM + lk8;
  const float* xrow = x + (size_t)(row0 + prow) * IN_F + pfq * 2;

  char* const rowbase = (char*)&A0[0] + prow * (LDA * 2);   // byte base in A0
  const int a1off = (int)((char*)&A1[0] - (char*)&A0[0]);   // buffer delta
  const int padoff = 192 + pfq * 4;                          // dump u32 in row pad

  auto produce = [&](int c, int boff, float2 xv) {
    char* rb = rowbase + boff;
    const f16x8 z8 = {};
    // zero this thread's 48-byte region (3 x b128)
    *(f16x8*)(rb + pfq * 48)      = z8;
    *(f16x8*)(rb + pfq * 48 + 16) = z8;
    *(f16x8*)(rb + pfq * 48 + 32) = z8;
    float sil[2];
    #pragma unroll
    for (int q = 0; q < 2; ++q) {
      const int i = c * 8 + pfq * 2 + q;
      const float xr = (q == 0) ? xv.x : xv.y;
      const float n  = (xr - mu) * rs * g_s[i] + b_s[i];
      const float v  = (n + 1.75f) * 4.0f;    // knots t_j = -1.75 + 0.25*j
      const float fj = floorf(v);
      const int j    = (int)fj;               // may be far out of [0,14): handled by slot dump
      const float u  = v - fj;
      const float u2 = u * u, u3 = u2 * u;
      const float w0 = (1.0f / 6.0f) * (1.0f - 3.0f * u + 3.0f * u2 - u3);
      const float w1 = (1.0f / 6.0f) * (3.0f * u3 - 6.0f * u2 + 4.0f);
      const float w2 = (1.0f / 6.0f) * (-3.0f * u3 + 3.0f * u2 + 3.0f * u + 1.0f);
      const float w3 = (1.0f / 6.0f) * u3;
      // window [w0..w3] occupies halves p..p+3 of this feature's 12-half field
      const int p  = j - 3;
      const int s0 = p >> 1;                  // arithmetic shift = floor div
      const bool odd = (p & 1);
      const unsigned W0 = pack2(w0, w1);
      const unsigned W1 = pack2(w2, w3);
      const unsigned v0 = odd ? (W0 << 16) : W0;
      const unsigned v1 = odd ? ((W0 >> 16) | (W1 << 16)) : W1;
      const unsigned v2 = odd ? (W1 >> 16) : 0u;
      const int featoff = pfq * 48 + q * 24;
      // three b32 slot writes; out-of-range slots -> row pad (dump)
      {
        const int s = s0;
        const int off = ((unsigned)s <= 5u) ? (featoff + s * 4) : padoff;
        *(unsigned*)(rb + off) = v0;
      }
      {
        const int s = s0 + 1;
        const int off = ((unsigned)s <= 5u) ? (featoff + s * 4) : padoff;
        *(unsigned*)(rb + off) = v1;
      }
      {
        const int s = s0 + 2;
        const int off = ((unsigned)s <= 5u) ? (featoff + s * 4) : padoff;
        *(unsigned*)(rb + off) = v2;
      }
      sil[q] = xr * __builtin_amdgcn_rcpf(1.0f + __expf(-xr));
    }
    // silu AFTER window writes (half 11 may have been touched by a window)
    ((_Float16*)rb)[pfq * 24 + 11] = (_Float16)sil[0];
    ((_Float16*)rb)[pfq * 24 + 23] = (_Float16)sil[1];
  };

  auto loadB = [&](int c, f16x8* bf) {
    const _Float16* wk = wbase + c * BKH;
    #pragma unroll
    for (int fk = 0; fk < 3; ++fk)
      #pragma unroll
      for (int fn = 0; fn < 4; ++fn)
        bf[fk * 4 + fn] = *(const f16x8*)(wk + (size_t)fn * 16 * KDIM + fk * 32);
  };

  auto domfma = [&](const _Float16* buf, const f16x8* bf) {
    #pragma unroll
    for (int fk = 0; fk < 3; ++fk) {
      f16x8 a[4];
      #pragma unroll
      for (int fm = 0; fm < 4; ++fm)
        a[fm] = *(const f16x8*)&buf[(fm * 16 + lrow) * LDA + fk * 32 + lk8];
      #pragma unroll
      for (int fm = 0; fm < 4; ++fm)
        #pragma unroll
        for (int fn = 0; fn < 4; ++fn)
          acc[fm][fn] = __builtin_amdgcn_mfma_f32_16x16x32_f16(a[fm], bf[fk * 4 + fn], acc[fm][fn], 0, 0, 0);
    }
  };

  // prologue: B for chunk 0 in flight; x for chunks 0,1 in flight
  f16x8 bA[12], bB[12];
  loadB(0, bA);
  float2 xv0 = *(const float2*)(xrow);
  float2 xv1 = *(const float2*)(xrow + 8);

  produce(0, 0, xv0);
  __syncthreads();

  for (int c = 0; c < NCHUNK; c += 2) {
    // interval 1: issue B(c+1), x(c+2); produce(c+1)->A1; mfma(c)<-A0,bA
    loadB(c + 1, bB);
    if (c + 2 < NCHUNK) xv0 = *(const float2*)(xrow + (c + 2) * 8);
    produce(c + 1, a1off, xv1);
    domfma(A0, bA);
    __syncthreads();
    // interval 2: issue B(c+2), x(c+3); produce(c+2)->A0; mfma(c+1)<-A1,bB
    if (c + 2 < NCHUNK) loadB(c + 2, bA);
    if (c + 3 < NCHUNK) xv1 = *(const float2*)(xrow + (c + 3) * 8);
    if (c + 2 < NCHUNK) produce(c + 2, 0, xv0);
    domfma(A1, bB);
    __syncthreads();
  }

  // ---- epilogue: D lane layout col = lane&15, row = (lane>>4)*4 + r ----
  const int orow0 = row0 + (lane >> 4) * 4;
  const int ocol0 = wc * 64 + lrow;
  #pragma unroll
  for (int fm = 0; fm < 4; ++fm)
    #pragma unroll
    for (int fn = 0; fn < 4; ++fn)
      #pragma unroll
      for (int r = 0; r < 4; ++r)
        out[(size_t)(orow0 + fm * 16 + r) * OUT_F + ocol0 + fn * 16] = acc[fm][fn][r];
}

extern "C" void kernel_launch(void* const* d_in, const int* in_sizes, int n_in,
                              void* d_out, int out_size, void* d_ws, size_t ws_size,
                              hipStream_t stream) {
  const float* x      = (const float*)d_in[0];
  const float* gamma  = (const float*)d_in[1];
  const float* beta   = (const float*)d_in[2];
  const float* coeff  = (const float*)d_in[3];
  const float* base_w = (const float*)d_in[4];
  float* out = (float*)d_out;
  _Float16* W2 = (_Float16*)d_ws;   // 3072*256*2 = 1.5 MB of workspace

  prep_w<<<dim3(OUT_F), dim3(256), 0, stream>>>(coeff, base_w, W2);
  kan_fused<<<dim3(32768 / BM), dim3(256), 0, stream>>>(x, gamma, beta, W2, out);
}

// Round 9
// 100.513 us; speedup vs baseline: 1.9387x; 1.2751x over previous
//
#include <hip/hip_runtime.h>
#include <hip/hip_bf16.h>

typedef _Float16 f16x8 __attribute__((ext_vector_type(8)));
typedef float f32x4 __attribute__((ext_vector_type(4)));

#define BM 128      // rows per block
#define BKH 96      // K-halves per chunk (8 features x 12 slots)
#define LDA 104     // A row stride (halves): 13x16B -> odd granule walk
#define LDB 104     // B row stride (halves)
#define NCHUNK 32   // 3072 / 96
#define IN_F 256
#define OUT_F 256
#define KDIM 3072   // 256 * 12

// Build W2[o][k] fp16, k = i*12 + m ; m<11 -> coeff[o][i][m], m==11 -> base_w[o][i]
__global__ __launch_bounds__(256) void prep_w(const float* __restrict__ coeff,
                                              const float* __restrict__ base_w,
                                              _Float16* __restrict__ W2) {
  const int o = blockIdx.x;
  for (int k2 = threadIdx.x; k2 < KDIM / 2; k2 += 256) {
    const int k = k2 * 2;
    float v0, v1;
    {
      const int i = k / 12, m = k % 12;
      v0 = (m == 11) ? base_w[o * IN_F + i] : coeff[(o * IN_F + i) * 11 + m];
    }
    {
      const int k1 = k + 1;
      const int i = k1 / 12, m = k1 % 12;
      v1 = (m == 11) ? base_w[o * IN_F + i] : coeff[(o * IN_F + i) * 11 + m];
    }
    union { _Float16 h[2]; unsigned int u; } p;
    p.h[0] = (_Float16)v0;
    p.h[1] = (_Float16)v1;
    *(unsigned int*)&W2[(size_t)o * KDIM + k] = p.u;
  }
}

__global__ __launch_bounds__(512, 2) void kan_fused(const float* __restrict__ x,
                                                    const float* __restrict__ gamma,
                                                    const float* __restrict__ beta,
                                                    const _Float16* __restrict__ W2,
                                                    float* __restrict__ out) {
  __shared__ _Float16 A0[BM * LDA], A1[BM * LDA];       // 53.2 KB
  __shared__ _Float16 B0[OUT_F * LDB], B1[OUT_F * LDB]; // 104 KB
  __shared__ float mu_s[BM], rs_s[BM];

  const int tid  = threadIdx.x;
  const int lane = tid & 63;
  const int wid  = tid >> 6;          // 0..7
  const int row0 = blockIdx.x * BM;

  // ---- LayerNorm stats: one wave per row ----
  for (int rr = wid; rr < BM; rr += 8) {
    const float4 v = *(const float4*)(x + (size_t)(row0 + rr) * IN_F + lane * 4);
    float s  = v.x + v.y + v.z + v.w;
    float sq = v.x * v.x + v.y * v.y + v.z * v.z + v.w * v.w;
    #pragma unroll
    for (int off = 32; off >= 1; off >>= 1) {
      s  += __shfl_xor(s, off);
      sq += __shfl_xor(sq, off);
    }
    if (lane == 0) {
      const float mu  = s * (1.0f / 256.0f);
      const float var = sq * (1.0f / 256.0f) - mu * mu;
      mu_s[rr] = mu;
      rs_s[rr] = 1.0f / sqrtf(var + 1e-5f);
    }
  }
  __syncthreads();                    // stats visible

  // wave roles: wr = row half, wc = col group; each wave 64x64 output
  const int wr   = wid >> 2;          // 0..1
  const int wc   = wid & 3;           // 0..3
  const int lrow = lane & 15;
  const int lk8  = (lane >> 4) * 8;

  f32x4 acc[4][4] = {};

  // production: 128 rows x 4 feature-pairs = 512 cells, 1 per thread
  const int prow = tid >> 2;          // 0..127
  const int pfq  = tid & 3;           // feature-pair within chunk
  const float mu = mu_s[prow], rs = rs_s[prow];
  const float* xrow = x + (size_t)(row0 + prow) * IN_F + pfq * 2;
  const float* grow = gamma + pfq * 2;
  const float* brow = beta + pfq * 2;

  // B staging: 256 rows x 2 half-rows; each thread 96 B = 6 x 16B
  const int bo = tid >> 1;            // 0..255 (out feature)
  const int bp = tid & 1;             // half-row
  const _Float16* bgsrc = W2 + (size_t)bo * KDIM + bp * 48;
  f16x8 breg[6];

  auto loadBreg = [&](int c) {
    const _Float16* s = bgsrc + c * BKH;
    #pragma unroll
    for (int j = 0; j < 6; ++j) breg[j] = *(const f16x8*)(s + j * 8);
  };
  auto writeBlds = [&](_Float16* Bb) {
    _Float16* d = &Bb[bo * LDB + bp * 48];
    #pragma unroll
    for (int j = 0; j < 6; ++j) *(f16x8*)(d + j * 8) = breg[j];
  };

  auto produce = [&](int c, _Float16* buf, float2 xv, float2 gv, float2 bv) {
    _Float16 h[24];
    #pragma unroll
    for (int q = 0; q < 2; ++q) {
      const float xr = (q == 0) ? xv.x : xv.y;
      const float gq = (q == 0) ? gv.x : gv.y;
      const float bq = (q == 0) ? bv.x : bv.y;
      const float n  = (xr - mu) * rs * gq + bq;
      const float v  = (n + 1.75f) * 4.0f;      // knots t_j = -1.75 + 0.25*j
      const float fj = floorf(v);
      const int j = (v >= 0.0f && v < 14.0f) ? (int)fj : 999; // out of grid -> zero basis
      const float u  = v - fj;
      const float u2 = u * u, u3 = u2 * u;
      const float w0 = (1.0f / 6.0f) * (1.0f - 3.0f * u + 3.0f * u2 - u3);
      const float w1 = (1.0f / 6.0f) * (3.0f * u3 - 6.0f * u2 + 4.0f);
      const float w2 = (1.0f / 6.0f) * (-3.0f * u3 + 3.0f * u2 + 3.0f * u + 1.0f);
      const float w3 = (1.0f / 6.0f) * u3;
      #pragma unroll
      for (int m = 0; m < 11; ++m) {            // tap index t = m - (j-3)
        const int t = m - j + 3;
        float w = 0.0f;
        w = (t == 0) ? w0 : w;
        w = (t == 1) ? w1 : w;
        w = (t == 2) ? w2 : w;
        w = (t == 3) ? w3 : w;
        h[q * 12 + m] = (_Float16)w;
      }
      h[q * 12 + 11] = (_Float16)(xr / (1.0f + __expf(-xr)));  // silu(raw x)
    }
    char* db = (char*)&buf[prow * LDA] + pfq * 48;
    *(f16x8*)(db)      = *(const f16x8*)&h[0];
    *(f16x8*)(db + 16) = *(const f16x8*)&h[8];
    *(f16x8*)(db + 32) = *(const f16x8*)&h[16];
  };

  auto domfma = [&](const _Float16* Ab, const _Float16* Bb) {
    #pragma unroll
    for (int fk = 0; fk < 3; ++fk) {
      f16x8 a[4], b[4];
      #pragma unroll
      for (int fm = 0; fm < 4; ++fm)
        a[fm] = *(const f16x8*)&Ab[(wr * 64 + fm * 16 + lrow) * LDA + fk * 32 + lk8];
      #pragma unroll
      for (int fn = 0; fn < 4; ++fn)
        b[fn] = *(const f16x8*)&Bb[(wc * 64 + fn * 16 + lrow) * LDB + fk * 32 + lk8];
      #pragma unroll
      for (int fm = 0; fm < 4; ++fm)
        #pragma unroll
        for (int fn = 0; fn < 4; ++fn)
          acc[fm][fn] = __builtin_amdgcn_mfma_f32_16x16x32_f16(a[fm], b[fn], acc[fm][fn], 0, 0, 0);
    }
  };

  // prologue: prefetch x/gamma/beta for chunks 0,1; stage B(0); produce A(0)
  float2 xv0 = *(const float2*)(xrow);
  float2 gv0 = *(const float2*)(grow);
  float2 bv0 = *(const float2*)(brow);
  float2 xv1 = *(const float2*)(xrow + 8);
  float2 gv1 = *(const float2*)(grow + 8);
  float2 bv1 = *(const float2*)(brow + 8);

  loadBreg(0);
  produce(0, A0, xv0, gv0, bv0);
  writeBlds(B0);
  __syncthreads();

  for (int c = 0; c < NCHUNK; c += 2) {
    // interval even: consume {A0,B0}=c ; build {A1,B1}=c+1 ; prefetch c+2
    {
      const int cp2 = (c + 2 < NCHUNK) ? (c + 2) : (NCHUNK - 1);
      loadBreg(c + 1);
      xv0 = *(const float2*)(xrow + cp2 * 8);
      gv0 = *(const float2*)(grow + cp2 * 8);
      bv0 = *(const float2*)(brow + cp2 * 8);
      produce(c + 1, A1, xv1, gv1, bv1);
      domfma(A0, B0);
      writeBlds(B1);
      __syncthreads();
    }
    // interval odd: consume {A1,B1}=c+1 ; build {A0,B0}=c+2 ; prefetch c+3
    {
      const int cp2 = (c + 2 < NCHUNK) ? (c + 2) : (NCHUNK - 1);
      const int cp3 = (c + 3 < NCHUNK) ? (c + 3) : (NCHUNK - 1);
      loadBreg(cp2);
      xv1 = *(const float2*)(xrow + cp3 * 8);
      gv1 = *(const float2*)(grow + cp3 * 8);
      bv1 = *(const float2*)(brow + cp3 * 8);
      produce(cp2, A0, xv0, gv0, bv0);
      domfma(A1, B1);
      writeBlds(B0);
      __syncthreads();
    }
  }

  // ---- epilogue: D lane layout col = lane&15, row = (lane>>4)*4 + r ----
  const int orow0 = row0 + wr * 64 + (lane >> 4) * 4;
  const int ocol0 = wc * 64 + lrow;
  #pragma unroll
  for (int fm = 0; fm < 4; ++fm)
    #pragma unroll
    for (int fn = 0; fn < 4; ++fn)
      #pragma unroll
      for (int r = 0; r < 4; ++r)
        out[(size_t)(orow0 + fm * 16 + r) * OUT_F + ocol0 + fn * 16] = acc[fm][fn][r];
}

extern "C" void kernel_launch(void* const* d_in, const int* in_sizes, int n_in,
                              void* d_out, int out_size, void* d_ws, size_t ws_size,
                              hipStream_t stream) {
  const float* x      = (const float*)d_in[0];
  const float* gamma  = (const float*)d_in[1];
  const float* beta   = (const float*)d_in[2];
  const float* coeff  = (const float*)d_in[3];
  const float* base_w = (const float*)d_in[4];
  float* out = (float*)d_out;
  _Float16* W2 = (_Float16*)d_ws;   // 3072*256*2 = 1.5 MB of workspace

  prep_w<<<dim3(OUT_F), dim3(256), 0, stream>>>(coeff, base_w, W2);
  kan_fused<<<dim3(32768 / BM), dim3(512), 0, stream>>>(x, gamma, beta, W2, out);
}

// Round 10
// 91.587 us; speedup vs baseline: 2.1277x; 1.0975x over previous
//
#include <hip/hip_runtime.h>
#include <hip/hip_bf16.h>

typedef _Float16 f16x8 __attribute__((ext_vector_type(8)));
typedef float f32x4 __attribute__((ext_vector_type(4)));

#define BM 128      // rows per block
#define BKH 96      // K-halves per chunk (8 features x 12 slots)
#define NCHUNK 32   // 3072 / 96
#define IN_F 256
#define OUT_F 256
#define KDIM 3072   // 256 * 12
// frag-order LDS: one "group" = 512 halves = 64 lanes x 8 halves (1 KB)
// A: 8 rowblks x 3 fk = 24 groups = 24 KB ; B: 16 colblks x 3 fk = 48 KB

// Build W2[o][k] fp16, k = i*12 + m ; m<11 -> coeff[o][i][m], m==11 -> base_w[o][i]
__global__ __launch_bounds__(256) void prep_w(const float* __restrict__ coeff,
                                              const float* __restrict__ base_w,
                                              _Float16* __restrict__ W2) {
  const int o = blockIdx.x;
  for (int k2 = threadIdx.x; k2 < KDIM / 2; k2 += 256) {
    const int k = k2 * 2;
    float v0, v1;
    {
      const int i = k / 12, m = k % 12;
      v0 = (m == 11) ? base_w[o * IN_F + i] : coeff[(o * IN_F + i) * 11 + m];
    }
    {
      const int k1 = k + 1;
      const int i = k1 / 12, m = k1 % 12;
      v1 = (m == 11) ? base_w[o * IN_F + i] : coeff[(o * IN_F + i) * 11 + m];
    }
    union { _Float16 h[2]; unsigned int u; } p;
    p.h[0] = (_Float16)v0;
    p.h[1] = (_Float16)v1;
    *(unsigned int*)&W2[(size_t)o * KDIM + k] = p.u;
  }
}

__global__ __launch_bounds__(512, 2) void kan_fused(const float* __restrict__ x,
                                                    const float* __restrict__ gamma,
                                                    const float* __restrict__ beta,
                                                    const _Float16* __restrict__ W2,
                                                    float* __restrict__ out) {
  __shared__ _Float16 A0[24 * 512], A1[24 * 512];   // 24 KB each
  __shared__ _Float16 B0[48 * 512], B1[48 * 512];   // 48 KB each
  __shared__ float mu_s[BM], rs_s[BM];

  const int tid  = threadIdx.x;
  const int lane = tid & 63;
  const int wid  = tid >> 6;          // 0..7
  const int row0 = blockIdx.x * BM;

  // ---- LayerNorm stats: one wave per row ----
  for (int rr = wid; rr < BM; rr += 8) {
    const float4 v = *(const float4*)(x + (size_t)(row0 + rr) * IN_F + lane * 4);
    float s  = v.x + v.y + v.z + v.w;
    float sq = v.x * v.x + v.y * v.y + v.z * v.z + v.w * v.w;
    #pragma unroll
    for (int off = 32; off >= 1; off >>= 1) {
      s  += __shfl_xor(s, off);
      sq += __shfl_xor(sq, off);
    }
    if (lane == 0) {
      const float mu  = s * (1.0f / 256.0f);
      const float var = sq * (1.0f / 256.0f) - mu * mu;
      mu_s[rr] = mu;
      rs_s[rr] = 1.0f / sqrtf(var + 1e-5f);
    }
  }
  __syncthreads();                    // stats visible

  // wave roles: wr = row half, wc = col group; each wave 64x64 output
  const int wr   = wid >> 2;          // 0..1
  const int wc   = wid & 3;           // 0..3
  const int lrow = lane & 15;

  f32x4 acc[4][4] = {};

  // producer map (lrow-fastest so write octets hit 8 distinct quads):
  const int plrow = tid & 15;
  const int pfq   = (tid >> 4) & 3;   // feature-pair within chunk
  const int prb   = tid >> 6;         // row block 0..7 (== wid)
  const int prow  = prb * 16 + plrow; // 0..127
  const float mu = mu_s[prow], rs = rs_s[prow];
  const float* xrow = x + (size_t)(row0 + prow) * IN_F + pfq * 2;
  const float* grow = gamma + pfq * 2;
  const float* brow = beta + pfq * 2;

  // producer dest offsets (halves), one per 8-half group k8 = pfq*3 + j
  int aoff[3];
  #pragma unroll
  for (int j = 0; j < 3; ++j) {
    const int k8 = pfq * 3 + j;
    aoff[j] = (prb * 3 + (k8 >> 2)) * 512 + (k8 & 3) * 128 + plrow * 8;
  }

  // B staging: 256 cols x 2 half-rows; each thread 96 B = 6 x 16B
  const int bo = tid >> 1;            // 0..255 (out feature / column)
  const int bp = tid & 1;             // half of the 96-half chunk row
  const int bcb = bo >> 4, blc = bo & 15;
  const _Float16* bgsrc = W2 + (size_t)bo * KDIM + bp * 48;
  int boff[6];
  #pragma unroll
  for (int j = 0; j < 6; ++j) {
    const int k8 = bp * 6 + j;
    boff[j] = (bcb * 3 + (k8 >> 2)) * 512 + (k8 & 3) * 128 + blc * 8;
  }
  f16x8 breg[6];

  auto loadBreg = [&](int c) {
    const _Float16* s = bgsrc + c * BKH;
    #pragma unroll
    for (int j = 0; j < 6; ++j) breg[j] = *(const f16x8*)(s + j * 8);
  };
  auto writeBlds = [&](_Float16* Bb) {
    #pragma unroll
    for (int j = 0; j < 6; ++j) *(f16x8*)&Bb[boff[j]] = breg[j];
  };

  auto produce = [&](int c, _Float16* buf, float2 xv, float2 gv, float2 bv) {
    _Float16 h[24];
    #pragma unroll
    for (int q = 0; q < 2; ++q) {
      const float xr = (q == 0) ? xv.x : xv.y;
      const float gq = (q == 0) ? gv.x : gv.y;
      const float bq = (q == 0) ? bv.x : bv.y;
      const float n  = (xr - mu) * rs * gq + bq;
      const float v  = (n + 1.75f) * 4.0f;      // knots t_j = -1.75 + 0.25*j
      const float fj = floorf(v);
      const int j = (v >= 0.0f && v < 14.0f) ? (int)fj : 999; // out of grid -> zero basis
      const float u  = v - fj;
      const float u2 = u * u, u3 = u2 * u;
      const float w0 = (1.0f / 6.0f) * (1.0f - 3.0f * u + 3.0f * u2 - u3);
      const float w1 = (1.0f / 6.0f) * (3.0f * u3 - 6.0f * u2 + 4.0f);
      const float w2 = (1.0f / 6.0f) * (-3.0f * u3 + 3.0f * u2 + 3.0f * u + 1.0f);
      const float w3 = (1.0f / 6.0f) * u3;
      #pragma unroll
      for (int m = 0; m < 11; ++m) {            // tap index t = m - (j-3)
        const int t = m - j + 3;
        float w = 0.0f;
        w = (t == 0) ? w0 : w;
        w = (t == 1) ? w1 : w;
        w = (t == 2) ? w2 : w;
        w = (t == 3) ? w3 : w;
        h[q * 12 + m] = (_Float16)w;
      }
      h[q * 12 + 11] = (_Float16)(xr / (1.0f + __expf(-xr)));  // silu(raw x)
    }
    *(f16x8*)&buf[aoff[0]] = *(const f16x8*)&h[0];
    *(f16x8*)&buf[aoff[1]] = *(const f16x8*)&h[8];
    *(f16x8*)&buf[aoff[2]] = *(const f16x8*)&h[16];
  };

  auto domfma = [&](const _Float16* Ab, const _Float16* Bb) {
    #pragma unroll
    for (int fk = 0; fk < 3; ++fk) {
      f16x8 a[4], b[4];
      #pragma unroll
      for (int fm = 0; fm < 4; ++fm)
        a[fm] = *(const f16x8*)&Ab[((wr * 4 + fm) * 3 + fk) * 512 + lane * 8];
      #pragma unroll
      for (int fn = 0; fn < 4; ++fn)
        b[fn] = *(const f16x8*)&Bb[((wc * 4 + fn) * 3 + fk) * 512 + lane * 8];
      #pragma unroll
      for (int fm = 0; fm < 4; ++fm)
        #pragma unroll
        for (int fn = 0; fn < 4; ++fn)
          acc[fm][fn] = __builtin_amdgcn_mfma_f32_16x16x32_f16(a[fm], b[fn], acc[fm][fn], 0, 0, 0);
    }
  };

  // prologue: prefetch x/gamma/beta for chunks 0,1; stage B(0); produce A(0)
  float2 xv0 = *(const float2*)(xrow);
  float2 gv0 = *(const float2*)(grow);
  float2 bv0 = *(const float2*)(brow);
  float2 xv1 = *(const float2*)(xrow + 8);
  float2 gv1 = *(const float2*)(grow + 8);
  float2 bv1 = *(const float2*)(brow + 8);

  loadBreg(0);
  produce(0, A0, xv0, gv0, bv0);
  writeBlds(B0);
  __syncthreads();

  for (int c = 0; c < NCHUNK; c += 2) {
    // interval even: consume {A0,B0}=c ; build {A1,B1}=c+1 ; prefetch c+2
    {
      const int cp2 = (c + 2 < NCHUNK) ? (c + 2) : (NCHUNK - 1);
      loadBreg(c + 1);
      xv0 = *(const float2*)(xrow + cp2 * 8);
      gv0 = *(const float2*)(grow + cp2 * 8);
      bv0 = *(const float2*)(brow + cp2 * 8);
      produce(c + 1, A1, xv1, gv1, bv1);
      domfma(A0, B0);
      writeBlds(B1);
      __syncthreads();
    }
    // interval odd: consume {A1,B1}=c+1 ; build {A0,B0}=c+2 ; prefetch c+3
    {
      const int cp2 = (c + 2 < NCHUNK) ? (c + 2) : (NCHUNK - 1);
      const int cp3 = (c + 3 < NCHUNK) ? (c + 3) : (NCHUNK - 1);
      loadBreg(cp2);
      xv1 = *(const float2*)(xrow + cp3 * 8);
      gv1 = *(const float2*)(grow + cp3 * 8);
      bv1 = *(const float2*)(brow + cp3 * 8);
      produce(cp2, A0, xv0, gv0, bv0);
      domfma(A1, B1);
      writeBlds(B0);
      __syncthreads();
    }
  }

  // ---- epilogue: D lane layout col = lane&15, row = (lane>>4)*4 + r ----
  const int orow0 = row0 + wr * 64 + (lane >> 4) * 4;
  const int ocol0 = wc * 64 + lrow;
  #pragma unroll
  for (int fm = 0; fm < 4; ++fm)
    #pragma unroll
    for (int fn = 0; fn < 4; ++fn)
      #pragma unroll
      for (int r = 0; r < 4; ++r)
        out[(size_t)(orow0 + fm * 16 + r) * OUT_F + ocol0 + fn * 16] = acc[fm][fn][r];
}

extern "C" void kernel_launch(void* const* d_in, const int* in_sizes, int n_in,
                              void* d_out, int out_size, void* d_ws, size_t ws_size,
                              hipStream_t stream) {
  const float* x      = (const float*)d_in[0];
  const float* gamma  = (const float*)d_in[1];
  const float* beta   = (const float*)d_in[2];
  const float* coeff  = (const float*)d_in[3];
  const float* base_w = (const float*)d_in[4];
  float* out = (float*)d_out;
  _Float16* W2 = (_Float16*)d_ws;   // 3072*256*2 = 1.5 MB of workspace

  prep_w<<<dim3(OUT_F), dim3(256), 0, stream>>>(coeff, base_w, W2);
  kan_fused<<<dim3(32768 / BM), dim3(512), 0, stream>>>(x, gamma, beta, W2, out);
}